// Round 4
// baseline (521.545 us; speedup 1.0000x reference)
//
#include <hip/hip_runtime.h>
#include <cstddef>
#include <cstdint>

// ---------------------------------------------------------------------------
// GraphClassifier round 4.
// fc layers: 1024-thread blocks, 16 waves = 4 K-groups x 4 col-groups.
// Register-only double-buffered K-loop (no LDS, no barriers until the final
// cross-K-group reduction). A read once from HBM. BN fused into att gather.
// att: one wave per row, ballot scan, no atomics/barriers.
// ---------------------------------------------------------------------------

#define NN 4096
#define HDIM 64
#define ENC_OUT (NN * HDIM)   // 262144 = 2^18

typedef _Float16 half8 __attribute__((ext_vector_type(8)));
typedef _Float16 half4 __attribute__((ext_vector_type(4)));
typedef float v4f __attribute__((ext_vector_type(4)));

struct GemmP {
    const void*     A[2];     // fp32 (fc1) or fp16, row-major [M,K]
    const _Float16* B[2];     // weight fp16, row-major [N,K]
    const float*    bias[2];
    void*           C[2];     // fp16 or fp32 per HALF_OUT
};

// ---------------------------------------------------------------------------
// MFMA GEMM: C[m,n] = act(bias[n] + sum_k A[m,k]*B[n,k])
// Block: 1024 thr = 16 waves. wave = kg*4 + cg is wrong order; we use
// cg = wave&3 (column group, owns NI*16 cols), kg = wave>>2 (K quarter).
// BM=32 (2 m-frags/wave), BN = NI*64 = full N. Each wave runs its K-quarter
// with register double-buffering; compiler inserts fine-grained vmcnt.
// End: 3-round LDS tree reduction across kg, epilogue by kg==0 waves.
// ---------------------------------------------------------------------------
template<int NI, bool A16, bool HALF_OUT, bool RELU>
__global__ __launch_bounds__(1024) void gemm_kernel(GemmP p, int K)
{
    constexpr int N = NI * 64;
    __shared__ float red[8 * NI * 512];   // 8 regions of 512*NI floats

    const int tid  = threadIdx.x;
    const int wave = tid >> 6, lane = tid & 63;
    const int l16  = lane & 15, quad = lane >> 4;
    const int cg   = wave & 3;       // column group: cols [cg*NI*16, ...)
    const int kg   = wave >> 2;      // K quarter
    const int enc  = blockIdx.y;
    const int m0   = blockIdx.x * 32;

    const int Kq    = K >> 2;
    const int steps = Kq >> 5;                 // 32-K per step
    const int kbase = kg * Kq + quad * 8;

    const _Float16* __restrict__ Bp = p.B[enc];

    // double-buffer registers (next step's loads in flight)
    half8  nb[NI];
    half8  na[2];
    float4 nf[4];

    auto issue = [&](int s) {
        const int k = kbase + s * 32;
#pragma unroll
        for (int ni = 0; ni < NI; ni++) {
            const int col = cg * (NI * 16) + ni * 16 + l16;
            nb[ni] = *(const half8*)(Bp + (size_t)col * K + k);
        }
        if constexpr (A16) {
            const _Float16* A = (const _Float16*)p.A[enc];
            na[0] = *(const half8*)(A + (size_t)(m0 + l16) * K + k);
            na[1] = *(const half8*)(A + (size_t)(m0 + 16 + l16) * K + k);
        } else {
            const float* A = (const float*)p.A[enc];
            nf[0] = *(const float4*)(A + (size_t)(m0 + l16) * K + k);
            nf[1] = *(const float4*)(A + (size_t)(m0 + l16) * K + k + 4);
            nf[2] = *(const float4*)(A + (size_t)(m0 + 16 + l16) * K + k);
            nf[3] = *(const float4*)(A + (size_t)(m0 + 16 + l16) * K + k + 4);
        }
    };

    v4f acc[2][NI];
#pragma unroll
    for (int mi = 0; mi < 2; mi++)
#pragma unroll
        for (int ni = 0; ni < NI; ni++) acc[mi][ni] = (v4f){0.f, 0.f, 0.f, 0.f};

    issue(0);

    for (int s = 0; s < steps; s++) {
        // consume buffered data into cur regs (forces wait on step s only)
        half8 a0, a1;
        if constexpr (A16) {
            a0 = na[0]; a1 = na[1];
        } else {
            a0[0] = (_Float16)nf[0].x; a0[1] = (_Float16)nf[0].y;
            a0[2] = (_Float16)nf[0].z; a0[3] = (_Float16)nf[0].w;
            a0[4] = (_Float16)nf[1].x; a0[5] = (_Float16)nf[1].y;
            a0[6] = (_Float16)nf[1].z; a0[7] = (_Float16)nf[1].w;
            a1[0] = (_Float16)nf[2].x; a1[1] = (_Float16)nf[2].y;
            a1[2] = (_Float16)nf[2].z; a1[3] = (_Float16)nf[2].w;
            a1[4] = (_Float16)nf[3].x; a1[5] = (_Float16)nf[3].y;
            a1[6] = (_Float16)nf[3].z; a1[7] = (_Float16)nf[3].w;
        }
        half8 cb[NI];
#pragma unroll
        for (int ni = 0; ni < NI; ni++) cb[ni] = nb[ni];

        // next step's loads go in flight across the MFMAs below
        if (s + 1 < steps) issue(s + 1);

#pragma unroll
        for (int ni = 0; ni < NI; ni++) {
            acc[0][ni] = __builtin_amdgcn_mfma_f32_16x16x32_f16(a0, cb[ni], acc[0][ni], 0, 0, 0);
            acc[1][ni] = __builtin_amdgcn_mfma_f32_16x16x32_f16(a1, cb[ni], acc[1][ni], 0, 0, 0);
        }
    }

    // ---- cross-kg tree reduction in LDS (once per kernel) ----------------
    auto dump = [&](int region) {
#pragma unroll
        for (int mi = 0; mi < 2; mi++)
#pragma unroll
            for (int ni = 0; ni < NI; ni++)
#pragma unroll
                for (int i = 0; i < 4; i++)
                    red[region * (512 * NI) + ((mi * NI + ni) * 4 + i) * 64 + lane]
                        = acc[mi][ni][i];
    };
    auto gather = [&](int region) {
#pragma unroll
        for (int mi = 0; mi < 2; mi++)
#pragma unroll
            for (int ni = 0; ni < NI; ni++)
#pragma unroll
                for (int i = 0; i < 4; i++)
                    acc[mi][ni][i]
                        += red[region * (512 * NI) + ((mi * NI + ni) * 4 + i) * 64 + lane];
    };

    if (kg >= 2) dump((kg - 2) * 4 + cg);
    __syncthreads();
    if (kg < 2) gather(kg * 4 + cg);
    __syncthreads();
    if (kg == 1) dump(cg);
    __syncthreads();

    if (kg == 0) {
        gather(cg);
#pragma unroll
        for (int mi = 0; mi < 2; mi++)
#pragma unroll
            for (int ni = 0; ni < NI; ni++) {
                const int col = cg * (NI * 16) + ni * 16 + l16;
                const float bv = p.bias[enc][col];
#pragma unroll
                for (int i = 0; i < 4; i++) {
                    const int row = m0 + mi * 16 + quad * 4 + i;
                    float v = acc[mi][ni][i] + bv;
                    if (RELU) v = fmaxf(v, 0.f);
                    if constexpr (HALF_OUT)
                        ((_Float16*)p.C[enc])[(size_t)row * N + col] = (_Float16)v;
                    else
                        ((float*)p.C[enc])[(size_t)row * N + col] = v;
                }
            }
    }
}

// ---------------------------------------------------------------------------
// fused fp32 -> fp16 conversion for all six weight matrices
// ---------------------------------------------------------------------------
struct CvtJob { const float* s; _Float16* d; int n4; };
struct CvtP { CvtJob j[6]; };

__global__ __launch_bounds__(256) void cvt_all_kernel(CvtP p)
{
    int i = blockIdx.x * 256 + threadIdx.x;
#pragma unroll
    for (int k = 0; k < 6; k++) {
        if (i < p.j[k].n4) {
            float4 v = ((const float4*)p.j[k].s)[i];
            half4 h;
            h[0] = (_Float16)v.x; h[1] = (_Float16)v.y;
            h[2] = (_Float16)v.z; h[3] = (_Float16)v.w;
            ((half4*)p.j[k].d)[i] = h;
            return;
        }
        i -= p.j[k].n4;
    }
}

// ---------------------------------------------------------------------------
// BatchNorm stats (two-phase, coalesced)
// ---------------------------------------------------------------------------
__global__ __launch_bounds__(256) void bn_stat1_kernel(const float* __restrict__ h3,
                                                       float* __restrict__ bnp)
{
    const int enc = blockIdx.y, b = blockIdx.x;
    const int c = threadIdx.x & 63, rg = threadIdx.x >> 6;
    const float* h = h3 + (size_t)enc * ENC_OUT + (size_t)b * 128 * HDIM;
    float s = 0.f, q = 0.f;
    for (int r = rg; r < 128; r += 4) {
        float v = h[(size_t)r * HDIM + c];
        s += v; q += v * v;
    }
    __shared__ float ss[4][64], sq[4][64];
    ss[rg][c] = s; sq[rg][c] = q;
    __syncthreads();
    if (threadIdx.x < 64) {
        float S = ss[0][c] + ss[1][c] + ss[2][c] + ss[3][c];
        float Q = sq[0][c] + sq[1][c] + sq[2][c] + sq[3][c];
        bnp[(size_t)(enc * 32 + b) * 128 + c] = S;
        bnp[(size_t)(enc * 32 + b) * 128 + 64 + c] = Q;
    }
}

__global__ void bn_stat2_kernel(const float* __restrict__ bnp, float* __restrict__ stats)
{
    const int enc = blockIdx.x, c = threadIdx.x;  // 64 threads
    float s = 0.f, q = 0.f;
    for (int b = 0; b < 32; b++) {
        s += bnp[(size_t)(enc * 32 + b) * 128 + c];
        q += bnp[(size_t)(enc * 32 + b) * 128 + 64 + c];
    }
    float mean = s * (1.f / NN);
    float var = q * (1.f / NN) - mean * mean;
    stats[enc * 128 + c] = mean;
    stats[enc * 128 + 64 + c] = rsqrtf(var + 1e-5f);
}

// ---------------------------------------------------------------------------
// Self-attention, wave-per-row, BN fused into the gather.
// lane c = column. Ballot over 64-wide adj chunks; neighbor walk is
// wave-uniform (mask identical across lanes) -> no divergence.
// Reads h3 (pre-BN) + stats; hn never materialized.
// ---------------------------------------------------------------------------
__global__ __launch_bounds__(256) void att_kernel(const float* __restrict__ adj1,
                                                  const float* __restrict__ adj2,
                                                  const float* __restrict__ al1,
                                                  const float* __restrict__ al2,
                                                  const float* __restrict__ h3,
                                                  const float* __restrict__ stats,
                                                  const float* __restrict__ g0,
                                                  const float* __restrict__ g1,
                                                  const float* __restrict__ be0,
                                                  const float* __restrict__ be1,
                                                  float* __restrict__ out)
{
    const int enc = blockIdx.y;
    const int i = blockIdx.x * 4 + (threadIdx.x >> 6);
    const int c = threadIdx.x & 63;

    const float* adj = enc ? adj2 : adj1;
    const float* al  = enc ? al2 : al1;
    const float* h   = h3 + (size_t)enc * ENC_OUT;

    const float m  = stats[enc * 128 + c];
    const float rs = stats[enc * 128 + 64 + c];
    const float ga = (enc ? g1 : g0)[c];
    const float bb = (enc ? be1 : be0)[c];
    const float sa = rs * ga;
    const float sb = bb - m * sa;

    const float* arow = adj + (size_t)i * NN;
    const float* wrow = al + (size_t)i * NN;

    float acc = 0.f;
    int cnt = 0;
    for (int base = 0; base < NN; base += 64) {
        const float a = arow[base + c];
        unsigned long long mask = __ballot(a == 1.0f);
        cnt += __popcll(mask);
        while (mask) {
            const int j = base + (int)__builtin_ctzll(mask);
            mask &= mask - 1;
            const float wj = wrow[j];
            const float hv = fmaxf(h[(size_t)j * HDIM + c] * sa + sb, 0.f);
            acc += wj * hv;
        }
    }
    const float hi = fmaxf(h[(size_t)i * HDIM + c] * sa + sb, 0.f);
    out[(size_t)enc * ENC_OUT + (size_t)i * HDIM + c]
        = cnt ? acc / (float)cnt + hi : 0.f;
}

// ---------------------------------------------------------------------------
// Head: two-phase deterministic reduction
// ---------------------------------------------------------------------------
#define FDIM (2 * ENC_OUT)

__global__ __launch_bounds__(256) void final_partial_kernel(const float* __restrict__ feat,
                                                            const float* __restrict__ Wc,
                                                            float* __restrict__ partial)
{
    const int gt = blockIdx.x * 256 + threadIdx.x;   // 131072 threads
    float p0 = 0.f, p1 = 0.f;
    for (int f = gt; f < FDIM; f += 131072) {
        float x = feat[f];
        p0 += x * Wc[f];
        p1 += x * Wc[FDIM + f];
    }
    __shared__ float r0[256], r1[256];
    r0[threadIdx.x] = p0;
    r1[threadIdx.x] = p1;
    __syncthreads();
    for (int off = 128; off > 0; off >>= 1) {
        if (threadIdx.x < off) {
            r0[threadIdx.x] += r0[threadIdx.x + off];
            r1[threadIdx.x] += r1[threadIdx.x + off];
        }
        __syncthreads();
    }
    if (threadIdx.x == 0) {
        partial[blockIdx.x * 2 + 0] = r0[0];
        partial[blockIdx.x * 2 + 1] = r1[0];
    }
}

__global__ void final_reduce_kernel(const float* __restrict__ partial,
                                    const float* __restrict__ bc,
                                    float* __restrict__ out)
{
    const int t = threadIdx.x;
    if (t < 2) {
        float s = bc[t];
        for (int b = 0; b < 512; b++) s += partial[b * 2 + t];
        out[t] = s;
    }
}

// ---------------------------------------------------------------------------

extern "C" void kernel_launch(void* const* d_in, const int* in_sizes, int n_in,
                              void* d_out, int out_size, void* d_ws, size_t ws_size,
                              hipStream_t stream)
{
    const float* x1    = (const float*)d_in[0];
    const float* x2    = (const float*)d_in[1];
    const float* adj1  = (const float*)d_in[2];
    const float* adj2  = (const float*)d_in[3];
    const float* e1_W1 = (const float*)d_in[4];
    const float* e1_b1 = (const float*)d_in[5];
    const float* e1_W2 = (const float*)d_in[6];
    const float* e1_b2 = (const float*)d_in[7];
    const float* e1_W3 = (const float*)d_in[8];
    const float* e1_b3 = (const float*)d_in[9];
    const float* e1_g  = (const float*)d_in[10];
    const float* e1_be = (const float*)d_in[11];
    const float* e2_W1 = (const float*)d_in[12];
    const float* e2_b1 = (const float*)d_in[13];
    const float* e2_W2 = (const float*)d_in[14];
    const float* e2_b2 = (const float*)d_in[15];
    const float* e2_W3 = (const float*)d_in[16];
    const float* e2_b3 = (const float*)d_in[17];
    const float* e2_g  = (const float*)d_in[18];
    const float* e2_be = (const float*)d_in[19];
    const float* alpha1 = (const float*)d_in[20];
    const float* alpha2 = (const float*)d_in[21];
    const float* Wc    = (const float*)d_in[22];
    const float* bc    = (const float*)d_in[23];
    (void)in_sizes; (void)n_in; (void)out_size; (void)ws_size;

    // ---- workspace layout (~14.4 MB) -------------------------------------
    char* w = (char*)d_ws;
    _Float16* W1h = (_Float16*)w;  w += (size_t)2 * 256 * NN * 2;      // 4 MB
    _Float16* W2h = (_Float16*)w;  w += (size_t)2 * 128 * 256 * 2;     // 128 KB
    _Float16* W3h = (_Float16*)w;  w += (size_t)2 * 64 * 128 * 2;      // 32 KB
    _Float16* h1h = (_Float16*)w;  w += (size_t)2 * NN * 256 * 2;      // 4 MB
    _Float16* h2h = (_Float16*)w;  w += (size_t)2 * NN * 128 * 2;      // 2 MB
    float* h3  = (float*)w;        w += (size_t)2 * ENC_OUT * 4;       // 2 MB
    float* att = (float*)w;        w += (size_t)2 * ENC_OUT * 4;       // 2 MB
    float* bnp = (float*)w;        w += (size_t)2 * 32 * 128 * 4;      // 32 KB
    float* stats = (float*)w;      w += 256 * 4;
    float* hpart = (float*)w;      w += 1024 * 4;

    const dim3 blk(256);
    const dim3 blk1k(1024);

    // ---- weight conversion -----------------------------------------------
    CvtP cp;
    cp.j[0] = { e1_W1, W1h,             262144 };
    cp.j[1] = { e2_W1, W1h + 256 * NN,  262144 };
    cp.j[2] = { e1_W2, W2h,             8192 };
    cp.j[3] = { e2_W2, W2h + 128 * 256, 8192 };
    cp.j[4] = { e1_W3, W3h,             2048 };
    cp.j[5] = { e2_W3, W3h + 64 * 128,  2048 };
    cvt_all_kernel<<<dim3(2128), blk, 0, stream>>>(cp);

    // ---- fc1: [4096,4096] -> 256, ReLU, fp16 out -------------------------
    GemmP p1 = { {x1, x2}, {W1h, W1h + 256 * NN}, {e1_b1, e2_b1},
                 {h1h, h1h + (size_t)NN * 256} };
    gemm_kernel<4, false, true, true><<<dim3(NN / 32, 2), blk1k, 0, stream>>>(p1, NN);

    // ---- fc2: [4096,256] -> 128, ReLU, fp16 out --------------------------
    GemmP p2 = { {h1h, h1h + (size_t)NN * 256}, {W2h, W2h + 128 * 256}, {e1_b2, e2_b2},
                 {h2h, h2h + (size_t)NN * 128} };
    gemm_kernel<2, true, true, true><<<dim3(NN / 32, 2), blk1k, 0, stream>>>(p2, 256);

    // ---- fc3: [4096,128] -> 64, fp32 out (BN follows) --------------------
    GemmP p3 = { {h2h, h2h + (size_t)NN * 128}, {W3h, W3h + 64 * 128}, {e1_b3, e2_b3},
                 {h3, h3 + ENC_OUT} };
    gemm_kernel<1, true, false, false><<<dim3(NN / 32, 2), blk1k, 0, stream>>>(p3, 128);

    // ---- BatchNorm stats (apply is fused into att) -----------------------
    bn_stat1_kernel<<<dim3(32, 2), blk, 0, stream>>>(h3, bnp);
    bn_stat2_kernel<<<dim3(2), dim3(64), 0, stream>>>(bnp, stats);

    // ---- self-attention (BN+ReLU fused) ----------------------------------
    att_kernel<<<dim3(NN / 4, 2), blk, 0, stream>>>(adj1, adj2, alpha1, alpha2,
                                                    h3, stats, e1_g, e2_g, e1_be, e2_be,
                                                    att);

    // ---- head ------------------------------------------------------------
    final_partial_kernel<<<dim3(512), blk, 0, stream>>>(att, Wc, hpart);
    final_reduce_kernel<<<dim3(1), dim3(64), 0, stream>>>(hpart, bc, (float*)d_out);
}